// Round 4
// baseline (2455.600 us; speedup 1.0000x reference)
//
#include <hip/hip_runtime.h>

#define NROWS 32768
#define DDIM  128
#define KCODES 1024
#define DECAY 0.99f
#define OMD   0.01f
#define EPS   1e-5f

// ws layout (floats): [counts 1024][esum 131072][en2h 1024][inv 1024]
#define WS_COUNTS 0
#define WS_ESUM   1024
#define WS_EN2H   (1024 + 131072)
#define WS_INV    (WS_EN2H + 1024)
#define WS_ZERO_FLOATS (1024 + 131072)   // zero counts+esum

// ---- K0: half squared norms of codebook rows; one wave per code ----
__global__ void norms_kernel(const float* __restrict__ embed, float* __restrict__ en2h) {
  int w = threadIdx.x >> 6;
  int lane = threadIdx.x & 63;
  int k = blockIdx.x * 4 + w;
  const float2* p = (const float2*)(embed + k * DDIM);
  float2 v = p[lane];
  float s = v.x * v.x + v.y * v.y;
  #pragma unroll
  for (int off = 32; off > 0; off >>= 1) s += __shfl_down(s, off, 64);
  if (lane == 0) en2h[k] = 0.5f * s;
}

// ---- K1: fused scan. Lane owns a QUARTER x-row (32 VGPRs, allocator-safe);
// 4-lane group owns one row; wave = 16 rows scans ALL 1024 codes, then does
// the full epilogue (ind, counts, quantize, esum) — no merge kernels. ----
__global__ __launch_bounds__(256, 2) void vq_fused(
    const float* __restrict__ x, const float* __restrict__ embed,
    const float* __restrict__ en2h,
    float* __restrict__ counts, float* __restrict__ esum,
    float* __restrict__ out_q, float* __restrict__ out_ind) {
  const int lane = threadIdx.x & 63;
  const int wid  = threadIdx.x >> 6;
  const int q    = lane & 3;                 // quarter within row
  const int row  = blockIdx.x * 64 + wid * 16 + (lane >> 2);

  // own quarter-row into registers (8 float4 = 32 VGPRs)
  float4 xr[8];
  const float4* xp = (const float4*)(x + (size_t)row * DDIM + (q << 5));
  #pragma unroll
  for (int j = 0; j < 8; ++j) xr[j] = xp[j];

  const float4* ebase = (const float4*)(embed + (q << 5));  // + k*128 floats per code

  float bestv = -3.4e38f;
  int besti = 0;
  #pragma unroll 2
  for (int k = 0; k < KCODES; ++k) {
    const float4* ek = ebase + (k << 5);     // (k*128)/4 float4s
    float a0 = 0.f, a1 = 0.f, a2 = 0.f, a3 = 0.f;
    #pragma unroll
    for (int j = 0; j < 8; ++j) {
      float4 e4 = ek[j];
      a0 += xr[j].x * e4.x;
      a1 += xr[j].y * e4.y;
      a2 += xr[j].z * e4.z;
      a3 += xr[j].w * e4.w;
    }
    float s = (a0 + a1) + (a2 + a3);
    s += __shfl_xor(s, 1, 64);               // fold 4 quarters -> full dot
    s += __shfl_xor(s, 2, 64);
    s -= en2h[k];                            // uniform scalar load
    if (s > bestv) { bestv = s; besti = k; } // strict >: first (lowest) max
  }

  // ---- fused epilogue: all 4 lanes of a group hold identical (bestv,besti)
  if (q == 0) {
    out_ind[row] = (float)besti;
    unsafeAtomicAdd(counts + besti, 1.0f);   // native global_atomic_add_f32
  }
  // quantize gather-write: group writes its row from the winning code
  const float4* ew = (const float4*)(embed + (size_t)besti * DDIM + (q << 5));
  float4* qp = (float4*)(out_q + (size_t)row * DDIM + (q << 5));
  #pragma unroll
  for (int j = 0; j < 8; ++j) qp[j] = ew[j];
  // esum scatter: lane adds its resident x quarter
  float* sp = esum + (size_t)besti * DDIM + (q << 5);
  #pragma unroll
  for (int j = 0; j < 8; ++j) {
    unsafeAtomicAdd(sp + 4 * j + 0, xr[j].x);
    unsafeAtomicAdd(sp + 4 * j + 1, xr[j].y);
    unsafeAtomicAdd(sp + 4 * j + 2, xr[j].z);
    unsafeAtomicAdd(sp + 4 * j + 3, xr[j].w);
  }
}

// ---- K2: new_cluster_size, total, inverse smoothed ----
__global__ void fin1(const float* __restrict__ counts, const float* __restrict__ cs,
                     float* __restrict__ out_ncs, float* __restrict__ inv) {
  __shared__ float wsum[16];
  int tid = threadIdx.x;
  int lane = tid & 63, w = tid >> 6;
  float ncs = cs[tid] * DECAY + OMD * counts[tid];
  out_ncs[tid] = ncs;
  float s = ncs;
  #pragma unroll
  for (int off = 32; off > 0; off >>= 1) s += __shfl_down(s, off, 64);
  if (lane == 0) wsum[w] = s;
  __syncthreads();
  if (tid == 0) {
    float t = 0.f;
    #pragma unroll
    for (int i = 0; i < 16; ++i) t += wsum[i];
    wsum[0] = t;
  }
  __syncthreads();
  float total = wsum[0];
  inv[tid] = (total + (float)KCODES * EPS) / ((ncs + EPS) * total);
}

// ---- K3: new_embed_avg + new_embed ----
__global__ void fin2(const float* __restrict__ ea, const float* __restrict__ esum,
                     const float* __restrict__ inv,
                     float* __restrict__ out_nea, float* __restrict__ out_ne) {
  int gid = blockIdx.x * 256 + threadIdx.x;  // 0..32767, 4 elems each
  int base = gid * 4;
  int k = base >> 7;
  float4 a = *(const float4*)(ea + base);
  float4 s = *(const float4*)(esum + base);
  float iv = inv[k];
  float4 nea;
  nea.x = a.x * DECAY + OMD * s.x; nea.y = a.y * DECAY + OMD * s.y;
  nea.z = a.z * DECAY + OMD * s.z; nea.w = a.w * DECAY + OMD * s.w;
  *(float4*)(out_nea + base) = nea;
  float4 ne;
  ne.x = nea.x * iv; ne.y = nea.y * iv; ne.z = nea.z * iv; ne.w = nea.w * iv;
  *(float4*)(out_ne + base) = ne;
}

extern "C" void kernel_launch(void* const* d_in, const int* in_sizes, int n_in,
                              void* d_out, int out_size, void* d_ws, size_t ws_size,
                              hipStream_t stream) {
  const float* x     = (const float*)d_in[0];
  const float* embed = (const float*)d_in[1];
  const float* cs    = (const float*)d_in[2];
  const float* ea    = (const float*)d_in[3];

  float* out     = (float*)d_out;
  float* out_q   = out;                       // 4194304
  float* out_ind = out_q + 4194304;           // 32768
  float* out_ncs = out_ind + 32768;           // 1024
  float* out_nea = out_ncs + 1024;            // 131072
  float* out_ne  = out_nea + 131072;          // 131072

  float* ws     = (float*)d_ws;
  float* counts = ws + WS_COUNTS;
  float* esum   = ws + WS_ESUM;
  float* en2h   = ws + WS_EN2H;
  float* inv    = ws + WS_INV;

  hipMemsetAsync(ws, 0, (size_t)WS_ZERO_FLOATS * sizeof(float), stream);
  norms_kernel<<<KCODES / 4, 256, 0, stream>>>(embed, en2h);
  vq_fused<<<NROWS / 64, 256, 0, stream>>>(x, embed, en2h, counts, esum, out_q, out_ind);
  fin1<<<1, 1024, 0, stream>>>(counts, cs, out_ncs, inv);
  fin2<<<NROWS / 256, 256, 0, stream>>>(ea, esum, inv, out_nea, out_ne);
}

// Round 5
// 346.838 us; speedup vs baseline: 7.0800x; 7.0800x over previous
//
#include <hip/hip_runtime.h>

#define NROWS 32768
#define DDIM  128
#define KCODES 1024
#define DECAY 0.99f
#define OMD   0.01f
#define EPS   1e-5f

// ws layout: [counts f32 1024][esum f32 131072][en2h f32 1024][inv f32 1024][codes i32 32768]
#define WS_COUNTS 0
#define WS_ESUM   1024
#define WS_EN2H   (1024 + 131072)
#define WS_INV    (WS_EN2H + 1024)
#define WS_CODES  (WS_INV + 1024)
#define WS_ZERO_FLOATS (1024 + 131072)   // zero counts+esum

// ---- K0: half squared norms of codebook rows; one wave per code ----
__global__ void norms_kernel(const float* __restrict__ embed, float* __restrict__ en2h) {
  int w = threadIdx.x >> 6;
  int lane = threadIdx.x & 63;
  int k = blockIdx.x * 4 + w;
  const float2* p = (const float2*)(embed + k * DDIM);
  float2 v = p[lane];
  float s = v.x * v.x + v.y * v.y;
  #pragma unroll
  for (int off = 32; off > 0; off >>= 1) s += __shfl_down(s, off, 64);
  if (lane == 0) en2h[k] = 0.5f * s;
}

// ---- K1: d-major LDS-tiled fp32 GEMM + argmax.
// Tile: 64 rows x 1024 codes (4 chunks of 256), K chunked by 32.
// Thread (tx=tid&31, ty=tid>>5): 8 codes (tx*8) x 8 rows (ty*8), acc 8x8.
// LDS d-major => fragment loads are ds_read_b128 with heavy broadcast. ----
__global__ __launch_bounds__(256, 4) void vq_gemm(
    const float* __restrict__ x, const float* __restrict__ embed,
    const float* __restrict__ en2h,
    float* __restrict__ counts, int* __restrict__ codes_out,
    float* __restrict__ out_ind) {
  __shared__ float smem[16384];           // 64 KB: xs[128][64] | es[32][256]
  float* xs = smem;                       // 8192 floats, d-major: xs[d*64 + row]
  float* es = smem + 8192;                // 8192 floats, d-major: es[d*256 + code]

  const int tid = threadIdx.x;
  const int tx = tid & 31;                // code group: codes tx*8 .. tx*8+7 (per chunk)
  const int ty = tid >> 5;                // row group: rows ty*8 .. ty*8+7
  const int row0 = blockIdx.x * 64;

  // ---- stage x tile once, transposed to d-major ----
  {
    int row_s = tid & 63;
    int dg = tid >> 6;                    // 4 d-groups of 32
    const float* xp = x + (size_t)(row0 + row_s) * DDIM + dg * 32;
    #pragma unroll
    for (int j = 0; j < 8; ++j) {
      float4 x4 = *(const float4*)(xp + j * 4);
      int d = dg * 32 + j * 4;
      xs[(d + 0) * 64 + row_s] = x4.x;
      xs[(d + 1) * 64 + row_s] = x4.y;
      xs[(d + 2) * 64 + row_s] = x4.z;
      xs[(d + 3) * 64 + row_s] = x4.w;
    }
  }

  float bestv[8]; int besti[8];
  #pragma unroll
  for (int r = 0; r < 8; ++r) { bestv[r] = -3.4e38f; besti[r] = 0; }

  for (int cc = 0; cc < 4; ++cc) {        // 4 chunks of 256 codes
    float acc[8][8];
    #pragma unroll
    for (int r = 0; r < 8; ++r)
      #pragma unroll
      for (int c = 0; c < 8; ++c) acc[r][c] = 0.f;

    for (int kk = 0; kk < 4; ++kk) {      // K chunks of 32
      __syncthreads();                    // es readers done (first iter: xs writes ordered)
      // stage es chunk transposed: thread = one code, 32 d's
      {
        const float* ep = embed + (size_t)(cc * 256 + tid) * DDIM + kk * 32;
        #pragma unroll
        for (int j = 0; j < 8; ++j) {
          float4 e4 = *(const float4*)(ep + j * 4);
          es[(j * 4 + 0) * 256 + tid] = e4.x;
          es[(j * 4 + 1) * 256 + tid] = e4.y;
          es[(j * 4 + 2) * 256 + tid] = e4.z;
          es[(j * 4 + 3) * 256 + tid] = e4.w;
        }
      }
      __syncthreads();
      const float* xsb = xs + (kk * 32) * 64 + ty * 8;
      const float* esb = es + tx * 8;
      #pragma unroll 2
      for (int dl = 0; dl < 32; ++dl) {
        float4 xa = *(const float4*)(xsb + dl * 64);
        float4 xb = *(const float4*)(xsb + dl * 64 + 4);
        float4 ea = *(const float4*)(esb + dl * 256);
        float4 eb = *(const float4*)(esb + dl * 256 + 4);
        float xr[8] = {xa.x, xa.y, xa.z, xa.w, xb.x, xb.y, xb.z, xb.w};
        float er[8] = {ea.x, ea.y, ea.z, ea.w, eb.x, eb.y, eb.z, eb.w};
        #pragma unroll
        for (int r = 0; r < 8; ++r)
          #pragma unroll
          for (int c = 0; c < 8; ++c)
            acc[r][c] += xr[r] * er[c];
      }
    }
    // fold this chunk into running best: score = x.e - 0.5|e|^2
    float4 nha = *(const float4*)(en2h + cc * 256 + tx * 8);
    float4 nhb = *(const float4*)(en2h + cc * 256 + tx * 8 + 4);
    float nh[8] = {nha.x, nha.y, nha.z, nha.w, nhb.x, nhb.y, nhb.z, nhb.w};
    #pragma unroll
    for (int c = 0; c < 8; ++c) {
      int code = cc * 256 + tx * 8 + c;
      #pragma unroll
      for (int r = 0; r < 8; ++r) {
        float s = acc[r][c] - nh[c];
        if (s > bestv[r] || (s == bestv[r] && code < besti[r])) {
          bestv[r] = s; besti[r] = code;
        }
      }
    }
  }

  // ---- cross-tx argmax reduction via LDS (reuse smem) ----
  __syncthreads();
  float* redv = smem;                     // [64 rows][32 tx]
  int*   redi = (int*)(smem + 2048);
  #pragma unroll
  for (int r = 0; r < 8; ++r) {
    int rg = ty * 8 + r;
    redv[rg * 32 + tx] = bestv[r];
    redi[rg * 32 + tx] = besti[r];
  }
  __syncthreads();
  if (tid < 64) {
    float bv = redv[tid * 32]; int bi = redi[tid * 32];
    #pragma unroll 4
    for (int t = 1; t < 32; ++t) {
      float v = redv[tid * 32 + t]; int ix = redi[tid * 32 + t];
      if (v > bv || (v == bv && ix < bi)) { bv = v; bi = ix; }
    }
    codes_out[row0 + tid] = bi;
    out_ind[row0 + tid] = (float)bi;
    unsafeAtomicAdd(counts + bi, 1.0f);
  }
}

// ---- K2: quantize gather-write + embed_sum scatter (native f32 atomics) ----
__global__ void post2(const int* __restrict__ codes,
                      const float* __restrict__ x, const float* __restrict__ embed,
                      float* __restrict__ esum, float* __restrict__ out_q) {
  int gid = blockIdx.x * 256 + threadIdx.x;   // 1,048,576 float4-groups
  int row = gid >> 5, c4 = gid & 31;
  int code = codes[row];
  float4 e = *(const float4*)(embed + code * DDIM + c4 * 4);
  *(float4*)(out_q + (size_t)gid * 4) = e;
  float4 xv = *(const float4*)(x + (size_t)gid * 4);
  float* ep = esum + code * DDIM + c4 * 4;
  unsafeAtomicAdd(ep + 0, xv.x);
  unsafeAtomicAdd(ep + 1, xv.y);
  unsafeAtomicAdd(ep + 2, xv.z);
  unsafeAtomicAdd(ep + 3, xv.w);
}

// ---- K3: new_cluster_size, total, inverse smoothed ----
__global__ void fin1(const float* __restrict__ counts, const float* __restrict__ cs,
                     float* __restrict__ out_ncs, float* __restrict__ inv) {
  __shared__ float wsum[16];
  int tid = threadIdx.x;
  int lane = tid & 63, w = tid >> 6;
  float ncs = cs[tid] * DECAY + OMD * counts[tid];
  out_ncs[tid] = ncs;
  float s = ncs;
  #pragma unroll
  for (int off = 32; off > 0; off >>= 1) s += __shfl_down(s, off, 64);
  if (lane == 0) wsum[w] = s;
  __syncthreads();
  if (tid == 0) {
    float t = 0.f;
    #pragma unroll
    for (int i = 0; i < 16; ++i) t += wsum[i];
    wsum[0] = t;
  }
  __syncthreads();
  float total = wsum[0];
  inv[tid] = (total + (float)KCODES * EPS) / ((ncs + EPS) * total);
}

// ---- K4: new_embed_avg + new_embed ----
__global__ void fin2(const float* __restrict__ ea, const float* __restrict__ esum,
                     const float* __restrict__ inv,
                     float* __restrict__ out_nea, float* __restrict__ out_ne) {
  int gid = blockIdx.x * 256 + threadIdx.x;  // 0..32767, 4 elems each
  int base = gid * 4;
  int k = base >> 7;
  float4 a = *(const float4*)(ea + base);
  float4 s = *(const float4*)(esum + base);
  float iv = inv[k];
  float4 nea;
  nea.x = a.x * DECAY + OMD * s.x; nea.y = a.y * DECAY + OMD * s.y;
  nea.z = a.z * DECAY + OMD * s.z; nea.w = a.w * DECAY + OMD * s.w;
  *(float4*)(out_nea + base) = nea;
  float4 ne;
  ne.x = nea.x * iv; ne.y = nea.y * iv; ne.z = nea.z * iv; ne.w = nea.w * iv;
  *(float4*)(out_ne + base) = ne;
}

extern "C" void kernel_launch(void* const* d_in, const int* in_sizes, int n_in,
                              void* d_out, int out_size, void* d_ws, size_t ws_size,
                              hipStream_t stream) {
  const float* x     = (const float*)d_in[0];
  const float* embed = (const float*)d_in[1];
  const float* cs    = (const float*)d_in[2];
  const float* ea    = (const float*)d_in[3];

  float* out     = (float*)d_out;
  float* out_q   = out;                       // 4194304
  float* out_ind = out_q + 4194304;           // 32768
  float* out_ncs = out_ind + 32768;           // 1024
  float* out_nea = out_ncs + 1024;            // 131072
  float* out_ne  = out_nea + 131072;          // 131072

  float* ws     = (float*)d_ws;
  float* counts = ws + WS_COUNTS;
  float* esum   = ws + WS_ESUM;
  float* en2h   = ws + WS_EN2H;
  float* inv    = ws + WS_INV;
  int*   codes  = (int*)(ws + WS_CODES);

  hipMemsetAsync(ws, 0, (size_t)WS_ZERO_FLOATS * sizeof(float), stream);
  norms_kernel<<<KCODES / 4, 256, 0, stream>>>(embed, en2h);
  vq_gemm<<<NROWS / 64, 256, 0, stream>>>(x, embed, en2h, counts, codes, out_ind);
  post2<<<(NROWS * 32) / 256, 256, 0, stream>>>(codes, x, embed, esum, out_q);
  fin1<<<1, 1024, 0, stream>>>(counts, cs, out_ncs, inv);
  fin2<<<NROWS / 256, 256, 0, stream>>>(ea, esum, inv, out_nea, out_ne);
}

// Round 6
// 306.427 us; speedup vs baseline: 8.0137x; 1.1319x over previous
//
#include <hip/hip_runtime.h>

#define NROWS 32768
#define DDIM  128
#define KCODES 1024
#define DECAY 0.99f
#define OMD   0.01f
#define EPS   1e-5f

// ws layout (float offsets):
//   [counts 1024][esum 131072][en2h 1024 -> later offs i32][inv 1024 -> earlier cursor i32][bucket i32 32768]
// lifetime check: en2h dead after vq_gemm (scan writes offs after);
//   cursor dead after scatter (fin1 writes inv after); bucket lives scan..esum_q.
#define WS_COUNTS 0
#define WS_ESUM   1024
#define WS_EN2H   (1024 + 131072)
#define WS_INV    (WS_EN2H + 1024)
#define WS_BUCKET (WS_INV + 1024)

// ---- K0: half squared norms of codebook rows; one wave per code ----
__global__ void norms_kernel(const float* __restrict__ embed, float* __restrict__ en2h) {
  int w = threadIdx.x >> 6;
  int lane = threadIdx.x & 63;
  int k = blockIdx.x * 4 + w;
  const float2* p = (const float2*)(embed + k * DDIM);
  float2 v = p[lane];
  float s = v.x * v.x + v.y * v.y;
  #pragma unroll
  for (int off = 32; off > 0; off >>= 1) s += __shfl_down(s, off, 64);
  if (lane == 0) en2h[k] = 0.5f * s;
}

// ---- K1: d-major LDS-tiled fp32 GEMM + argmax (unchanged from R5) ----
__global__ __launch_bounds__(256, 4) void vq_gemm(
    const float* __restrict__ x, const float* __restrict__ embed,
    const float* __restrict__ en2h,
    float* __restrict__ counts, float* __restrict__ out_ind) {
  __shared__ float smem[16384];           // 64 KB: xs[128][64] | es[32][256]
  float* xs = smem;                       // d-major: xs[d*64 + row]
  float* es = smem + 8192;                // d-major: es[d*256 + code]

  const int tid = threadIdx.x;
  const int tx = tid & 31;
  const int ty = tid >> 5;
  const int row0 = blockIdx.x * 64;

  {
    int row_s = tid & 63;
    int dg = tid >> 6;
    const float* xp = x + (size_t)(row0 + row_s) * DDIM + dg * 32;
    #pragma unroll
    for (int j = 0; j < 8; ++j) {
      float4 x4 = *(const float4*)(xp + j * 4);
      int d = dg * 32 + j * 4;
      xs[(d + 0) * 64 + row_s] = x4.x;
      xs[(d + 1) * 64 + row_s] = x4.y;
      xs[(d + 2) * 64 + row_s] = x4.z;
      xs[(d + 3) * 64 + row_s] = x4.w;
    }
  }

  float bestv[8]; int besti[8];
  #pragma unroll
  for (int r = 0; r < 8; ++r) { bestv[r] = -3.4e38f; besti[r] = 0; }

  for (int cc = 0; cc < 4; ++cc) {
    float acc[8][8];
    #pragma unroll
    for (int r = 0; r < 8; ++r)
      #pragma unroll
      for (int c = 0; c < 8; ++c) acc[r][c] = 0.f;

    for (int kk = 0; kk < 4; ++kk) {
      __syncthreads();
      {
        const float* ep = embed + (size_t)(cc * 256 + tid) * DDIM + kk * 32;
        #pragma unroll
        for (int j = 0; j < 8; ++j) {
          float4 e4 = *(const float4*)(ep + j * 4);
          es[(j * 4 + 0) * 256 + tid] = e4.x;
          es[(j * 4 + 1) * 256 + tid] = e4.y;
          es[(j * 4 + 2) * 256 + tid] = e4.z;
          es[(j * 4 + 3) * 256 + tid] = e4.w;
        }
      }
      __syncthreads();
      const float* xsb = xs + (kk * 32) * 64 + ty * 8;
      const float* esb = es + tx * 8;
      #pragma unroll 2
      for (int dl = 0; dl < 32; ++dl) {
        float4 xa = *(const float4*)(xsb + dl * 64);
        float4 xb = *(const float4*)(xsb + dl * 64 + 4);
        float4 ea = *(const float4*)(esb + dl * 256);
        float4 eb = *(const float4*)(esb + dl * 256 + 4);
        float xr[8] = {xa.x, xa.y, xa.z, xa.w, xb.x, xb.y, xb.z, xb.w};
        float er[8] = {ea.x, ea.y, ea.z, ea.w, eb.x, eb.y, eb.z, eb.w};
        #pragma unroll
        for (int r = 0; r < 8; ++r)
          #pragma unroll
          for (int c = 0; c < 8; ++c)
            acc[r][c] += xr[r] * er[c];
      }
    }
    float4 nha = *(const float4*)(en2h + cc * 256 + tx * 8);
    float4 nhb = *(const float4*)(en2h + cc * 256 + tx * 8 + 4);
    float nh[8] = {nha.x, nha.y, nha.z, nha.w, nhb.x, nhb.y, nhb.z, nhb.w};
    #pragma unroll
    for (int c = 0; c < 8; ++c) {
      int code = cc * 256 + tx * 8 + c;
      #pragma unroll
      for (int r = 0; r < 8; ++r) {
        float s = acc[r][c] - nh[c];
        if (s > bestv[r] || (s == bestv[r] && code < besti[r])) {
          bestv[r] = s; besti[r] = code;
        }
      }
    }
  }

  __syncthreads();
  float* redv = smem;
  int*   redi = (int*)(smem + 2048);
  #pragma unroll
  for (int r = 0; r < 8; ++r) {
    int rg = ty * 8 + r;
    redv[rg * 32 + tx] = bestv[r];
    redi[rg * 32 + tx] = besti[r];
  }
  __syncthreads();
  if (tid < 64) {
    float bv = redv[tid * 32]; int bi = redi[tid * 32];
    #pragma unroll 4
    for (int t = 1; t < 32; ++t) {
      float v = redv[tid * 32 + t]; int ix = redi[tid * 32 + t];
      if (v > bv || (v == bv && ix < bi)) { bv = v; bi = ix; }
    }
    out_ind[row0 + tid] = (float)bi;
    unsafeAtomicAdd(counts + bi, 1.0f);
  }
}

// ---- K2: exclusive prefix scan of counts -> bucket offsets + cursors ----
__global__ void scan1024(const float* __restrict__ counts,
                         int* __restrict__ offs, int* __restrict__ cursor) {
  __shared__ int tmp[1024];
  int tid = threadIdx.x;
  int c = (int)counts[tid];
  tmp[tid] = c;
  __syncthreads();
  for (int off = 1; off < 1024; off <<= 1) {
    int v = (tid >= off) ? tmp[tid - off] : 0;
    __syncthreads();
    tmp[tid] += v;
    __syncthreads();
  }
  int excl = tmp[tid] - c;
  offs[tid] = excl;
  cursor[tid] = excl;
}

// ---- K3: scatter row ids into per-code buckets (32K cheap int atomics) ----
__global__ void scatter_rows(const float* __restrict__ out_ind,
                             int* __restrict__ cursor, int* __restrict__ bucket) {
  int row = blockIdx.x * 256 + threadIdx.x;
  int code = (int)out_ind[row];
  int pos = atomicAdd(cursor + code, 1);
  bucket[pos] = row;
}

// ---- K4: per-code segmented reduction (esum) + fused quantize write.
// Block = one code, 256 thr = 8 row-chains x 32 float4-lanes. No atomics. ----
__global__ __launch_bounds__(256) void esum_q(
    const int* __restrict__ bucket, const int* __restrict__ offs,
    const float* __restrict__ counts, const float* __restrict__ x,
    const float* __restrict__ embed,
    float* __restrict__ esum, float* __restrict__ out_q) {
  __shared__ float4 part[256];
  const int code = blockIdx.x;
  const int t = threadIdx.x;
  const int c4 = t & 31;                  // float4 lane within row
  const int h = t >> 5;                   // chain id (8 chains)
  const int start = offs[code];
  const int cnt = (int)counts[code];
  const float4 e = *(const float4*)(embed + (size_t)code * DDIM + c4 * 4);
  float4 acc = {0.f, 0.f, 0.f, 0.f};
  for (int i = h; i < cnt; i += 8) {
    int row = bucket[start + i];
    const float4 xv = *(const float4*)(x + (size_t)row * DDIM + c4 * 4);
    *(float4*)(out_q + (size_t)row * DDIM + c4 * 4) = e;
    acc.x += xv.x; acc.y += xv.y; acc.z += xv.z; acc.w += xv.w;
  }
  part[t] = acc;
  __syncthreads();
  if (t < 32) {
    float4 s = part[t];
    #pragma unroll
    for (int hh = 1; hh < 8; ++hh) {
      float4 p = part[hh * 32 + t];
      s.x += p.x; s.y += p.y; s.z += p.z; s.w += p.w;
    }
    *(float4*)(esum + (size_t)code * DDIM + t * 4) = s;
  }
}

// ---- K5: new_cluster_size, total, inverse smoothed ----
__global__ void fin1(const float* __restrict__ counts, const float* __restrict__ cs,
                     float* __restrict__ out_ncs, float* __restrict__ inv) {
  __shared__ float wsum[16];
  int tid = threadIdx.x;
  int lane = tid & 63, w = tid >> 6;
  float ncs = cs[tid] * DECAY + OMD * counts[tid];
  out_ncs[tid] = ncs;
  float s = ncs;
  #pragma unroll
  for (int off = 32; off > 0; off >>= 1) s += __shfl_down(s, off, 64);
  if (lane == 0) wsum[w] = s;
  __syncthreads();
  if (tid == 0) {
    float t = 0.f;
    #pragma unroll
    for (int i = 0; i < 16; ++i) t += wsum[i];
    wsum[0] = t;
  }
  __syncthreads();
  float total = wsum[0];
  inv[tid] = (total + (float)KCODES * EPS) / ((ncs + EPS) * total);
}

// ---- K6: new_embed_avg + new_embed ----
__global__ void fin2(const float* __restrict__ ea, const float* __restrict__ esum,
                     const float* __restrict__ inv,
                     float* __restrict__ out_nea, float* __restrict__ out_ne) {
  int gid = blockIdx.x * 256 + threadIdx.x;
  int base = gid * 4;
  int k = base >> 7;
  float4 a = *(const float4*)(ea + base);
  float4 s = *(const float4*)(esum + base);
  float iv = inv[k];
  float4 nea;
  nea.x = a.x * DECAY + OMD * s.x; nea.y = a.y * DECAY + OMD * s.y;
  nea.z = a.z * DECAY + OMD * s.z; nea.w = a.w * DECAY + OMD * s.w;
  *(float4*)(out_nea + base) = nea;
  float4 ne;
  ne.x = nea.x * iv; ne.y = nea.y * iv; ne.z = nea.z * iv; ne.w = nea.w * iv;
  *(float4*)(out_ne + base) = ne;
}

extern "C" void kernel_launch(void* const* d_in, const int* in_sizes, int n_in,
                              void* d_out, int out_size, void* d_ws, size_t ws_size,
                              hipStream_t stream) {
  const float* x     = (const float*)d_in[0];
  const float* embed = (const float*)d_in[1];
  const float* cs    = (const float*)d_in[2];
  const float* ea    = (const float*)d_in[3];

  float* out     = (float*)d_out;
  float* out_q   = out;                       // 4194304
  float* out_ind = out_q + 4194304;           // 32768
  float* out_ncs = out_ind + 32768;           // 1024
  float* out_nea = out_ncs + 1024;            // 131072
  float* out_ne  = out_nea + 131072;          // 131072

  float* ws     = (float*)d_ws;
  float* counts = ws + WS_COUNTS;
  float* esum   = ws + WS_ESUM;
  float* en2h   = ws + WS_EN2H;
  float* inv    = ws + WS_INV;
  int*   offs   = (int*)(ws + WS_EN2H);   // aliases en2h (dead after vq_gemm)
  int*   cursor = (int*)(ws + WS_INV);    // aliases inv (written later by fin1)
  int*   bucket = (int*)(ws + WS_BUCKET);

  hipMemsetAsync(counts, 0, KCODES * sizeof(float), stream);
  norms_kernel<<<KCODES / 4, 256, 0, stream>>>(embed, en2h);
  vq_gemm<<<NROWS / 64, 256, 0, stream>>>(x, embed, en2h, counts, out_ind);
  scan1024<<<1, 1024, 0, stream>>>(counts, offs, cursor);
  scatter_rows<<<NROWS / 256, 256, 0, stream>>>(out_ind, cursor, bucket);
  esum_q<<<KCODES, 256, 0, stream>>>(bucket, offs, counts, x, embed, esum, out_q);
  fin1<<<1, 1024, 0, stream>>>(counts, cs, out_ncs, inv);
  fin2<<<NROWS / 256, 256, 0, stream>>>(ea, esum, inv, out_nea, out_ne);
}

// Round 7
// 250.394 us; speedup vs baseline: 9.8069x; 1.2238x over previous
//
#include <hip/hip_runtime.h>

#define NROWS 32768
#define DDIM  128
#define KCODES 1024
#define DECAY 0.99f
#define OMD   0.01f
#define EPS   1e-5f

// ws layout (float offsets): [counts 1024][en2h 1024][offs i32 1024][cursor i32 1024][inv 1024][bucket i32 32768]
#define WS_COUNTS 0
#define WS_EN2H   1024
#define WS_OFFS   2048
#define WS_CURSOR 3072
#define WS_INV    4096
#define WS_BUCKET 5120

// ---- K0: half squared norms of codebook rows; one wave per code ----
__global__ void norms_kernel(const float* __restrict__ embed, float* __restrict__ en2h) {
  int w = threadIdx.x >> 6;
  int lane = threadIdx.x & 63;
  int k = blockIdx.x * 4 + w;
  const float2* p = (const float2*)(embed + k * DDIM);
  float2 v = p[lane];
  float s = v.x * v.x + v.y * v.y;
  #pragma unroll
  for (int off = 32; off > 0; off >>= 1) s += __shfl_down(s, off, 64);
  if (lane == 0) en2h[k] = 0.5f * s;
}

// ---- K1: d-major LDS-tiled fp32 GEMM + argmax, conflict-free fragments.
// Lane tx covers codes {4tx..4tx+3} and {128+4tx..131+4tx} per 256-chunk:
// es float4-cols tx and tx+32 -> stride-1 across lanes (no bank conflicts). ----
__global__ __launch_bounds__(256, 4) void vq_gemm(
    const float* __restrict__ x, const float* __restrict__ embed,
    const float* __restrict__ en2h,
    float* __restrict__ counts, float* __restrict__ out_ind) {
  __shared__ float smem[16384];           // 64 KB: xs[128][64] | es[32][256]
  float* xs = smem;                       // d-major: xs[d*64 + row]
  float* es = smem + 8192;                // d-major: es[d*256 + code]

  const int tid = threadIdx.x;
  const int tx = tid & 31;
  const int ty = tid >> 5;
  const int row0 = blockIdx.x * 64;

  {
    int row_s = tid & 63;
    int dg = tid >> 6;
    const float* xp = x + (size_t)(row0 + row_s) * DDIM + dg * 32;
    #pragma unroll
    for (int j = 0; j < 8; ++j) {
      float4 x4 = *(const float4*)(xp + j * 4);
      int d = dg * 32 + j * 4;
      xs[(d + 0) * 64 + row_s] = x4.x;
      xs[(d + 1) * 64 + row_s] = x4.y;
      xs[(d + 2) * 64 + row_s] = x4.z;
      xs[(d + 3) * 64 + row_s] = x4.w;
    }
  }

  float bestv[8]; int besti[8];
  #pragma unroll
  for (int r = 0; r < 8; ++r) { bestv[r] = -3.4e38f; besti[r] = 0; }

  for (int cc = 0; cc < 4; ++cc) {
    float acc[8][8];
    #pragma unroll
    for (int r = 0; r < 8; ++r)
      #pragma unroll
      for (int c = 0; c < 8; ++c) acc[r][c] = 0.f;

    for (int kk = 0; kk < 4; ++kk) {
      __syncthreads();
      {
        const float* ep = embed + (size_t)(cc * 256 + tid) * DDIM + kk * 32;
        #pragma unroll
        for (int j = 0; j < 8; ++j) {
          float4 e4 = *(const float4*)(ep + j * 4);
          es[(j * 4 + 0) * 256 + tid] = e4.x;
          es[(j * 4 + 1) * 256 + tid] = e4.y;
          es[(j * 4 + 2) * 256 + tid] = e4.z;
          es[(j * 4 + 3) * 256 + tid] = e4.w;
        }
      }
      __syncthreads();
      const float* xsb = xs + (kk * 32) * 64 + ty * 8;
      const float* esb = es + tx * 4;     // cols tx and tx+32 (stride-1 across lanes)
      #pragma unroll 2
      for (int dl = 0; dl < 32; ++dl) {
        float4 xa = *(const float4*)(xsb + dl * 64);
        float4 xb = *(const float4*)(xsb + dl * 64 + 4);
        float4 ea = *(const float4*)(esb + dl * 256);
        float4 eb = *(const float4*)(esb + dl * 256 + 128);
        float xr[8] = {xa.x, xa.y, xa.z, xa.w, xb.x, xb.y, xb.z, xb.w};
        float er[8] = {ea.x, ea.y, ea.z, ea.w, eb.x, eb.y, eb.z, eb.w};
        #pragma unroll
        for (int r = 0; r < 8; ++r)
          #pragma unroll
          for (int c = 0; c < 8; ++c)
            acc[r][c] += xr[r] * er[c];
      }
    }
    float4 nha = *(const float4*)(en2h + cc * 256 + tx * 4);
    float4 nhb = *(const float4*)(en2h + cc * 256 + 128 + tx * 4);
    float nh[8] = {nha.x, nha.y, nha.z, nha.w, nhb.x, nhb.y, nhb.z, nhb.w};
    #pragma unroll
    for (int c = 0; c < 8; ++c) {
      int code = cc * 256 + (c < 4 ? tx * 4 + c : 128 + tx * 4 + (c - 4));
      #pragma unroll
      for (int r = 0; r < 8; ++r) {
        float s = acc[r][c] - nh[c];
        if (s > bestv[r] || (s == bestv[r] && code < besti[r])) {
          bestv[r] = s; besti[r] = code;
        }
      }
    }
  }

  __syncthreads();
  float* redv = smem;
  int*   redi = (int*)(smem + 2048);
  #pragma unroll
  for (int r = 0; r < 8; ++r) {
    int rg = ty * 8 + r;
    redv[rg * 32 + tx] = bestv[r];
    redi[rg * 32 + tx] = besti[r];
  }
  __syncthreads();
  if (tid < 64) {
    float bv = redv[tid * 32]; int bi = redi[tid * 32];
    #pragma unroll 4
    for (int t = 1; t < 32; ++t) {
      float v = redv[tid * 32 + t]; int ix = redi[tid * 32 + t];
      if (v > bv || (v == bv && ix < bi)) { bv = v; bi = ix; }
    }
    out_ind[row0 + tid] = (float)bi;
    unsafeAtomicAdd(counts + bi, 1.0f);
  }
}

// ---- K2: fused scan(counts) + EMA cluster-size + inv. One block, wave shfl-scan. ----
__global__ void scan_fin(const float* __restrict__ counts, const float* __restrict__ cs,
                         int* __restrict__ offs, int* __restrict__ cursor,
                         float* __restrict__ out_ncs, float* __restrict__ inv) {
  __shared__ float wtot[16];   // per-wave count totals
  __shared__ float ctot[16];   // per-wave cs totals
  int tid = threadIdx.x;
  int lane = tid & 63, w = tid >> 6;
  float c = counts[tid];
  float cv = cs[tid];
  float s = c, s2 = cv;
  #pragma unroll
  for (int off = 1; off < 64; off <<= 1) {   // wave inclusive scan (counts) + reduce (cs)
    float v = __shfl_up(s, off, 64);
    if (lane >= off) s += v;
    s2 += __shfl_xor(s2, off, 64) - s2 + ((void)0, 0.f), s2 = s2;  // placeholder no-op
  }
  // cs reduce separately (butterfly)
  float r2 = cv;
  #pragma unroll
  for (int off = 32; off > 0; off >>= 1) r2 += __shfl_down(r2, off, 64);
  if (lane == 63) wtot[w] = s;
  if (lane == 0)  ctot[w] = r2;
  __syncthreads();
  if (tid < 16) {
    float v = wtot[tid];
    #pragma unroll
    for (int off = 1; off < 16; off <<= 1) {
      float p = __shfl_up(v, off, 64);
      if (tid >= off) v += p;
    }
    wtot[tid] = v;               // inclusive scan of wave totals
    float t2 = ctot[tid];
    #pragma unroll
    for (int off = 8; off > 0; off >>= 1) t2 += __shfl_down(t2, off, 64);
    if (tid == 0) ctot[0] = t2;  // total cs
  }
  __syncthreads();
  float prefix = (w > 0) ? wtot[w - 1] : 0.f;
  int incl = (int)(s + prefix);
  int excl = incl - (int)c;
  offs[tid] = excl;
  cursor[tid] = excl;
  float ncs = cv * DECAY + OMD * c;
  out_ncs[tid] = ncs;
  float total = ctot[0] * DECAY + OMD * (float)NROWS;  // sum(ncs) exactly decomposed
  inv[tid] = (total + (float)KCODES * EPS) / ((ncs + EPS) * total);
}

// ---- K3: scatter row ids into per-code buckets ----
__global__ void scatter_rows(const float* __restrict__ out_ind,
                             int* __restrict__ cursor, int* __restrict__ bucket) {
  int row = blockIdx.x * 256 + threadIdx.x;
  int code = (int)out_ind[row];
  int pos = atomicAdd(cursor + code, 1);
  bucket[pos] = row;
}

// ---- K4: per-code segmented reduction + quantize write + fused EMA epilogue.
// Block = one code; 256 thr = 16 chains x 16 lanes (lane covers 8 floats). ----
__global__ __launch_bounds__(256) void esum_q_fin(
    const int* __restrict__ bucket, const int* __restrict__ offs,
    const float* __restrict__ counts, const float* __restrict__ x,
    const float* __restrict__ embed, const float* __restrict__ ea,
    const float* __restrict__ inv,
    float* __restrict__ out_q, float* __restrict__ out_nea, float* __restrict__ out_ne) {
  __shared__ float4 part[512];            // [16 chains][32 float4-cols]
  const int code = blockIdx.x;
  const int t = threadIdx.x;
  const int c8 = t & 15;                  // 8-float lane within row
  const int h = t >> 4;                   // chain id (16 chains)
  const int start = offs[code];
  const int cnt = (int)counts[code];
  const float4 e0 = *(const float4*)(embed + (size_t)code * DDIM + c8 * 8);
  const float4 e1 = *(const float4*)(embed + (size_t)code * DDIM + c8 * 8 + 4);
  float4 a0 = {0.f, 0.f, 0.f, 0.f}, a1 = {0.f, 0.f, 0.f, 0.f};
  int i = h;
  // unroll-2: two independent row loads in flight per chain
  for (; i + 16 < cnt; i += 32) {
    int rowA = bucket[start + i];
    int rowB = bucket[start + i + 16];
    const float* pa = x + (size_t)rowA * DDIM + c8 * 8;
    const float* pb = x + (size_t)rowB * DDIM + c8 * 8;
    float4 xa0 = *(const float4*)(pa), xa1 = *(const float4*)(pa + 4);
    float4 xb0 = *(const float4*)(pb), xb1 = *(const float4*)(pb + 4);
    float* qa = out_q + (size_t)rowA * DDIM + c8 * 8;
    float* qb = out_q + (size_t)rowB * DDIM + c8 * 8;
    *(float4*)(qa) = e0; *(float4*)(qa + 4) = e1;
    *(float4*)(qb) = e0; *(float4*)(qb + 4) = e1;
    a0.x += xa0.x + xb0.x; a0.y += xa0.y + xb0.y; a0.z += xa0.z + xb0.z; a0.w += xa0.w + xb0.w;
    a1.x += xa1.x + xb1.x; a1.y += xa1.y + xb1.y; a1.z += xa1.z + xb1.z; a1.w += xa1.w + xb1.w;
  }
  for (; i < cnt; i += 16) {
    int row = bucket[start + i];
    const float* pa = x + (size_t)row * DDIM + c8 * 8;
    float4 xa0 = *(const float4*)(pa), xa1 = *(const float4*)(pa + 4);
    float* qa = out_q + (size_t)row * DDIM + c8 * 8;
    *(float4*)(qa) = e0; *(float4*)(qa + 4) = e1;
    a0.x += xa0.x; a0.y += xa0.y; a0.z += xa0.z; a0.w += xa0.w;
    a1.x += xa1.x; a1.y += xa1.y; a1.z += xa1.z; a1.w += xa1.w;
  }
  part[h * 32 + c8 * 2]     = a0;
  part[h * 32 + c8 * 2 + 1] = a1;
  __syncthreads();
  if (t < 32) {
    float4 s = part[t];
    #pragma unroll
    for (int hh = 1; hh < 16; ++hh) {
      float4 p = part[hh * 32 + t];
      s.x += p.x; s.y += p.y; s.z += p.z; s.w += p.w;
    }
    // fused fin2 for this code's slice
    float iv = inv[code];
    int base = code * DDIM + t * 4;
    float4 a = *(const float4*)(ea + base);
    float4 nea;
    nea.x = a.x * DECAY + OMD * s.x; nea.y = a.y * DECAY + OMD * s.y;
    nea.z = a.z * DECAY + OMD * s.z; nea.w = a.w * DECAY + OMD * s.w;
    *(float4*)(out_nea + base) = nea;
    float4 ne;
    ne.x = nea.x * iv; ne.y = nea.y * iv; ne.z = nea.z * iv; ne.w = nea.w * iv;
    *(float4*)(out_ne + base) = ne;
  }
}

extern "C" void kernel_launch(void* const* d_in, const int* in_sizes, int n_in,
                              void* d_out, int out_size, void* d_ws, size_t ws_size,
                              hipStream_t stream) {
  const float* x     = (const float*)d_in[0];
  const float* embed = (const float*)d_in[1];
  const float* cs    = (const float*)d_in[2];
  const float* ea    = (const float*)d_in[3];

  float* out     = (float*)d_out;
  float* out_q   = out;                       // 4194304
  float* out_ind = out_q + 4194304;           // 32768
  float* out_ncs = out_ind + 32768;           // 1024
  float* out_nea = out_ncs + 1024;            // 131072
  float* out_ne  = out_nea + 131072;          // 131072

  float* ws     = (float*)d_ws;
  float* counts = ws + WS_COUNTS;
  float* en2h   = ws + WS_EN2H;
  int*   offs   = (int*)(ws + WS_OFFS);
  int*   cursor = (int*)(ws + WS_CURSOR);
  float* inv    = ws + WS_INV;
  int*   bucket = (int*)(ws + WS_BUCKET);

  hipMemsetAsync(counts, 0, KCODES * sizeof(float), stream);
  norms_kernel<<<KCODES / 4, 256, 0, stream>>>(embed, en2h);
  vq_gemm<<<NROWS / 64, 256, 0, stream>>>(x, embed, en2h, counts, out_ind);
  scan_fin<<<1, 1024, 0, stream>>>(counts, cs, offs, cursor, out_ncs, inv);
  scatter_rows<<<NROWS / 256, 256, 0, stream>>>(out_ind, cursor, bucket);
  esum_q_fin<<<KCODES, 256, 0, stream>>>(bucket, offs, counts, x, embed, ea, inv,
                                         out_q, out_nea, out_ne);
}

// Round 8
// 205.550 us; speedup vs baseline: 11.9465x; 1.2182x over previous
//
#include <hip/hip_runtime.h>

#define NROWS 32768
#define DDIM  128
#define KCODES 1024
#define DECAY 0.99f
#define OMD   0.01f
#define EPS   1e-5f

typedef __attribute__((ext_vector_type(8))) short short8;
typedef __attribute__((ext_vector_type(4))) float f32x4;

// ws layout (float offsets): [counts 1024][offs i32 1024][cursor i32 1024][inv 1024][en2h 1024][bucket i32 32768]
#define WS_COUNTS 0
#define WS_OFFS   1024
#define WS_CURSOR 2048
#define WS_INV    3072
#define WS_EN2H   4096
#define WS_BUCKET 5120

__device__ __forceinline__ unsigned short f2bf(float f) {
  union { float f; unsigned int u; } cv; cv.f = f;
  unsigned int u = cv.u;
  return (unsigned short)((u + 0x7fffu + ((u >> 16) & 1u)) >> 16);  // RNE
}

// ---- K1: split x into (xh, xl) bf16 pair, written in MFMA A-fragment layout.
// xpack frag (mt, kb): kb 0-3 = xh of cols kb*32.., kb 4-7 = xl. 16.78 MB
// (lives in out_q region; esum_q_fin overwrites it later). ----
__global__ __launch_bounds__(256) void pack_x(const float* __restrict__ x,
                                              ushort* __restrict__ xpack) {
  const int tid = threadIdx.x;
  const int w = tid >> 6, lane = tid & 63;
  const int mt = blockIdx.x * 4 + w;          // 2048 wave-tiles of 16 rows
  const int m = lane & 15, q = lane >> 4;
  const int row = mt * 16 + m;
  const float* xp = x + (size_t)row * DDIM + q * 8;
  #pragma unroll
  for (int kb = 0; kb < 4; ++kb) {
    float4 v0 = *(const float4*)(xp + kb * 32);
    float4 v1 = *(const float4*)(xp + kb * 32 + 4);
    float v[8] = {v0.x, v0.y, v0.z, v0.w, v1.x, v1.y, v1.z, v1.w};
    unsigned int h[8], l[8];
    #pragma unroll
    for (int j = 0; j < 8; ++j) {
      h[j] = f2bf(v[j]);
      float fh = __uint_as_float(h[j] << 16);
      l[j] = f2bf(v[j] - fh);
    }
    uint4 ph, pl;
    ph.x = h[0] | (h[1] << 16); ph.y = h[2] | (h[3] << 16);
    ph.z = h[4] | (h[5] << 16); ph.w = h[6] | (h[7] << 16);
    pl.x = l[0] | (l[1] << 16); pl.y = l[2] | (l[3] << 16);
    pl.z = l[4] | (l[5] << 16); pl.w = l[6] | (l[7] << 16);
    *(uint4*)(xpack + (((size_t)mt * 8 + kb) * 64 + lane) * 8)     = ph;
    *(uint4*)(xpack + (((size_t)mt * 8 + kb + 4) * 64 + lane) * 8) = pl;
  }
}

// ---- K2: split embed into (eh, el) in MFMA B-fragment layout + exact fp32 norms.
// epack frag (nt, kb): kb 0-3 = eh, kb 4-7 = el, kb 8-11 = eh (dup). 786 KB
// (lives in out_nea/out_ne region; esum_q_fin overwrites later). ----
__global__ __launch_bounds__(256) void pack_e(const float* __restrict__ embed,
                                              ushort* __restrict__ epack,
                                              float* __restrict__ en2h) {
  const int tid = threadIdx.x;
  const int w = tid >> 6, lane = tid & 63;
  const int nt = blockIdx.x * 4 + w;          // 64 tiles of 16 codes
  const int m = lane & 15, q = lane >> 4;
  const int row = nt * 16 + m;
  const float* ep = embed + (size_t)row * DDIM + q * 8;
  float ss = 0.f;
  #pragma unroll
  for (int kb = 0; kb < 4; ++kb) {
    float4 v0 = *(const float4*)(ep + kb * 32);
    float4 v1 = *(const float4*)(ep + kb * 32 + 4);
    float v[8] = {v0.x, v0.y, v0.z, v0.w, v1.x, v1.y, v1.z, v1.w};
    unsigned int h[8], l[8];
    #pragma unroll
    for (int j = 0; j < 8; ++j) {
      ss += v[j] * v[j];
      h[j] = f2bf(v[j]);
      float fh = __uint_as_float(h[j] << 16);
      l[j] = f2bf(v[j] - fh);
    }
    uint4 ph, pl;
    ph.x = h[0] | (h[1] << 16); ph.y = h[2] | (h[3] << 16);
    ph.z = h[4] | (h[5] << 16); ph.w = h[6] | (h[7] << 16);
    pl.x = l[0] | (l[1] << 16); pl.y = l[2] | (l[3] << 16);
    pl.z = l[4] | (l[5] << 16); pl.w = l[6] | (l[7] << 16);
    *(uint4*)(epack + (((size_t)nt * 12 + kb) * 64 + lane) * 8)     = ph;  // eh seg0
    *(uint4*)(epack + (((size_t)nt * 12 + kb + 8) * 64 + lane) * 8) = ph;  // eh seg2
    *(uint4*)(epack + (((size_t)nt * 12 + kb + 4) * 64 + lane) * 8) = pl;  // el seg1
  }
  ss += __shfl_xor(ss, 16, 64);
  ss += __shfl_xor(ss, 32, 64);
  if (q == 0) en2h[row] = 0.5f * ss;
}

// ---- K3: MFMA scoring GEMM (K=384 compensated bf16) + argmax.
// 256 blocks x 4 waves; wave = 32 rows (2 M-tiles), scans all 1024 codes.
// B chunks (16 codes = 12 frag-rows = 12 KB) streamed via LDS, reg-dbuf. ----
__global__ __launch_bounds__(256) void vq_mfma(
    const ushort* __restrict__ xpack, const uint4* __restrict__ epack_u4,
    const float* __restrict__ en2h,
    float* __restrict__ counts, float* __restrict__ out_ind) {
  __shared__ short8 bs[768];          // 12 KB B chunk
  __shared__ float nh_lds[1024];      // 4 KB norms
  const int tid = threadIdx.x;
  const int w = tid >> 6, lane = tid & 63;
  const int c = lane & 15, q = lane >> 4;
  const int mt0 = blockIdx.x * 8 + w * 2;

  // A fragments: 2 M-tiles x 8 unique kb (xh 0-3, xl 4-7) = 64 VGPRs
  short8 a0[8], a1[8];
  const short8* ap = (const short8*)xpack;
  #pragma unroll
  for (int kb = 0; kb < 8; ++kb) {
    a0[kb] = ap[((size_t)mt0 * 8 + kb) * 64 + lane];
    a1[kb] = ap[((size_t)(mt0 + 1) * 8 + kb) * 64 + lane];
  }
  *(float4*)(nh_lds + tid * 4) = *(const float4*)(en2h + tid * 4);

  // prologue: chunk 0 into staging regs
  uint4 st0 = epack_u4[tid], st1 = epack_u4[tid + 256], st2 = epack_u4[tid + 512];

  float bestv[8]; int besti[8];
  #pragma unroll
  for (int r = 0; r < 8; ++r) { bestv[r] = -3.4e38f; besti[r] = 0; }

  uint4* bsu = (uint4*)bs;
  for (int nt = 0; nt < 64; ++nt) {
    bsu[tid] = st0; bsu[tid + 256] = st1; bsu[tid + 512] = st2;
    __syncthreads();                       // staging (and nh on nt=0) visible
    if (nt < 63) {                         // prefetch next chunk during compute
      const uint4* gp = epack_u4 + (size_t)(nt + 1) * 768;
      st0 = gp[tid]; st1 = gp[tid + 256]; st2 = gp[tid + 512];
    }
    f32x4 acc0 = {0.f, 0.f, 0.f, 0.f}, acc1 = {0.f, 0.f, 0.f, 0.f};
    #pragma unroll
    for (int kb = 0; kb < 12; ++kb) {      // K=384: [xh.eh | xh.el | xl.eh]
      short8 b = bs[kb * 64 + lane];
      int ai = kb < 4 ? kb : kb - 4;       // kb4-7 reuse xh, kb8-11 use xl
      acc0 = __builtin_amdgcn_mfma_f32_16x16x32_bf16(a0[ai], b, acc0, 0, 0, 0);
      acc1 = __builtin_amdgcn_mfma_f32_16x16x32_bf16(a1[ai], b, acc1, 0, 0, 0);
    }
    float nh = nh_lds[nt * 16 + c];
    int code = nt * 16 + c;
    #pragma unroll
    for (int r = 0; r < 4; ++r) {          // C/D: col=lane&15, row=q*4+reg
      float s0 = acc0[r] - nh;
      if (s0 > bestv[r])     { bestv[r] = s0;     besti[r] = code; }
      float s1 = acc1[r] - nh;
      if (s1 > bestv[4 + r]) { bestv[4 + r] = s1; besti[4 + r] = code; }
    }
    __syncthreads();                       // all reads done before next write
  }

  // cross-column argmax: butterfly over the 16 lanes sharing q
  #pragma unroll
  for (int off = 1; off < 16; off <<= 1) {
    #pragma unroll
    for (int r = 0; r < 8; ++r) {
      float ov = __shfl_xor(bestv[r], off, 64);
      int   oi = __shfl_xor(besti[r], off, 64);
      if (ov > bestv[r] || (ov == bestv[r] && oi < besti[r])) {
        bestv[r] = ov; besti[r] = oi;      // first-max (lowest idx) tie rule
      }
    }
  }
  if (c == 0) {
    const int rowbase = blockIdx.x * 128 + w * 32 + q * 4;
    #pragma unroll
    for (int r = 0; r < 8; ++r) {
      int grow = rowbase + (r < 4 ? 0 : 16) + (r & 3);
      out_ind[grow] = (float)besti[r];
      unsafeAtomicAdd(counts + besti[r], 1.0f);
    }
  }
}

// ---- K4: fused scan(counts) + EMA cluster-size + inv ----
__global__ void scan_fin(const float* __restrict__ counts, const float* __restrict__ cs,
                         int* __restrict__ offs, int* __restrict__ cursor,
                         float* __restrict__ out_ncs, float* __restrict__ inv) {
  __shared__ float wtot[16];
  __shared__ float ctot[16];
  int tid = threadIdx.x;
  int lane = tid & 63, w = tid >> 6;
  float cnum = counts[tid];
  float cv = cs[tid];
  float s = cnum;
  #pragma unroll
  for (int off = 1; off < 64; off <<= 1) {
    float v = __shfl_up(s, off, 64);
    if (lane >= off) s += v;
  }
  float r2 = cv;
  #pragma unroll
  for (int off = 32; off > 0; off >>= 1) r2 += __shfl_down(r2, off, 64);
  if (lane == 63) wtot[w] = s;
  if (lane == 0)  ctot[w] = r2;
  __syncthreads();
  if (tid < 16) {
    float v = wtot[tid];
    #pragma unroll
    for (int off = 1; off < 16; off <<= 1) {
      float p = __shfl_up(v, off, 64);
      if (tid >= off) v += p;
    }
    wtot[tid] = v;
    float t2 = ctot[tid];
    #pragma unroll
    for (int off = 8; off > 0; off >>= 1) t2 += __shfl_down(t2, off, 64);
    if (tid == 0) ctot[0] = t2;
  }
  __syncthreads();
  float prefix = (w > 0) ? wtot[w - 1] : 0.f;
  int excl = (int)(s + prefix) - (int)cnum;
  offs[tid] = excl;
  cursor[tid] = excl;
  float ncs = cv * DECAY + OMD * cnum;
  out_ncs[tid] = ncs;
  float total = ctot[0] * DECAY + OMD * (float)NROWS;
  inv[tid] = (total + (float)KCODES * EPS) / ((ncs + EPS) * total);
}

// ---- K5: scatter row ids into per-code buckets ----
__global__ void scatter_rows(const float* __restrict__ out_ind,
                             int* __restrict__ cursor, int* __restrict__ bucket) {
  int row = blockIdx.x * 256 + threadIdx.x;
  int code = (int)out_ind[row];
  int pos = atomicAdd(cursor + code, 1);
  bucket[pos] = row;
}

// ---- K6: per-code segmented reduction + quantize write + fused EMA epilogue ----
__global__ __launch_bounds__(256) void esum_q_fin(
    const int* __restrict__ bucket, const int* __restrict__ offs,
    const float* __restrict__ counts, const float* __restrict__ x,
    const float* __restrict__ embed, const float* __restrict__ ea,
    const float* __restrict__ inv,
    float* __restrict__ out_q, float* __restrict__ out_nea, float* __restrict__ out_ne) {
  __shared__ float4 part[512];
  const int code = blockIdx.x;
  const int t = threadIdx.x;
  const int c8 = t & 15;
  const int h = t >> 4;
  const int start = offs[code];
  const int cnt = (int)counts[code];
  const float4 e0 = *(const float4*)(embed + (size_t)code * DDIM + c8 * 8);
  const float4 e1 = *(const float4*)(embed + (size_t)code * DDIM + c8 * 8 + 4);
  float4 a0 = {0.f, 0.f, 0.f, 0.f}, a1 = {0.f, 0.f, 0.f, 0.f};
  int i = h;
  for (; i + 16 < cnt; i += 32) {
    int rowA = bucket[start + i];
    int rowB = bucket[start + i + 16];
    const float* pa = x + (size_t)rowA * DDIM + c8 * 8;
    const float* pb = x + (size_t)rowB * DDIM + c8 * 8;
    float4 xa0 = *(const float4*)(pa), xa1 = *(const float4*)(pa + 4);
    float4 xb0 = *(const float4*)(pb), xb1 = *(const float4*)(pb + 4);
    float* qa = out_q + (size_t)rowA * DDIM + c8 * 8;
    float* qb = out_q + (size_t)rowB * DDIM + c8 * 8;
    *(float4*)(qa) = e0; *(float4*)(qa + 4) = e1;
    *(float4*)(qb) = e0; *(float4*)(qb + 4) = e1;
    a0.x += xa0.x + xb0.x; a0.y += xa0.y + xb0.y; a0.z += xa0.z + xb0.z; a0.w += xa0.w + xb0.w;
    a1.x += xa1.x + xb1.x; a1.y += xa1.y + xb1.y; a1.z += xa1.z + xb1.z; a1.w += xa1.w + xb1.w;
  }
  for (; i < cnt; i += 16) {
    int row = bucket[start + i];
    const float* pa = x + (size_t)row * DDIM + c8 * 8;
    float4 xa0 = *(const float4*)(pa), xa1 = *(const float4*)(pa + 4);
    float* qa = out_q + (size_t)row * DDIM + c8 * 8;
    *(float4*)(qa) = e0; *(float4*)(qa + 4) = e1;
    a0.x += xa0.x; a0.y += xa0.y; a0.z += xa0.z; a0.w += xa0.w;
    a1.x += xa1.x; a1.y += xa1.y; a1.z += xa1.z; a1.w += xa1.w;
  }
  part[h * 32 + c8 * 2]     = a0;
  part[h * 32 + c8 * 2 + 1] = a1;
  __syncthreads();
  if (t < 32) {
    float4 s = part[t];
    #pragma unroll
    for (int hh = 1; hh < 16; ++hh) {
      float4 p = part[hh * 32 + t];
      s.x += p.x; s.y += p.y; s.z += p.z; s.w += p.w;
    }
    float iv = inv[code];
    int base = code * DDIM + t * 4;
    float4 a = *(const float4*)(ea + base);
    float4 nea;
    nea.x = a.x * DECAY + OMD * s.x; nea.y = a.y * DECAY + OMD * s.y;
    nea.z = a.z * DECAY + OMD * s.z; nea.w = a.w * DECAY + OMD * s.w;
    *(float4*)(out_nea + base) = nea;
    float4 ne;
    ne.x = nea.x * iv; ne.y = nea.y * iv; ne.z = nea.z * iv; ne.w = nea.w * iv;
    *(float4*)(out_ne + base) = ne;
  }
}

extern "C" void kernel_launch(void* const* d_in, const int* in_sizes, int n_in,
                              void* d_out, int out_size, void* d_ws, size_t ws_size,
                              hipStream_t stream) {
  const float* x     = (const float*)d_in[0];
  const float* embed = (const float*)d_in[1];
  const float* cs    = (const float*)d_in[2];
  const float* ea    = (const float*)d_in[3];

  float* out     = (float*)d_out;
  float* out_q   = out;                       // 4194304
  float* out_ind = out_q + 4194304;           // 32768
  float* out_ncs = out_ind + 32768;           // 1024
  float* out_nea = out_ncs + 1024;            // 131072
  float* out_ne  = out_nea + 131072;          // 131072

  float* ws     = (float*)d_ws;
  float* counts = ws + WS_COUNTS;
  int*   offs   = (int*)(ws + WS_OFFS);
  int*   cursor = (int*)(ws + WS_CURSOR);
  float* inv    = ws + WS_INV;
  float* en2h   = ws + WS_EN2H;
  int*   bucket = (int*)(ws + WS_BUCKET);

  // scratch aliased into d_out (both regions fully rewritten by esum_q_fin):
  ushort* xpack = (ushort*)out_q;             // 16.78 MB == out_q region exactly
  ushort* epack = (ushort*)out_nea;           // 786 KB inside out_nea+out_ne (1 MB)

  hipMemsetAsync(counts, 0, KCODES * sizeof(float), stream);
  pack_x<<<512, 256, 0, stream>>>(x, xpack);
  pack_e<<<16, 256, 0, stream>>>(embed, epack, en2h);
  vq_mfma<<<256, 256, 0, stream>>>(xpack, (const uint4*)epack, en2h, counts, out_ind);
  scan_fin<<<1, 1024, 0, stream>>>(counts, cs, offs, cursor, out_ncs, inv);
  scatter_rows<<<NROWS / 256, 256, 0, stream>>>(out_ind, cursor, bucket);
  esum_q_fin<<<KCODES, 256, 0, stream>>>(bucket, offs, counts, x, embed, ea, inv,
                                         out_q, out_nea, out_ne);
}

// Round 9
// 180.457 us; speedup vs baseline: 13.6077x; 1.1390x over previous
//
#include <hip/hip_runtime.h>

#define NROWS 32768
#define DDIM  128
#define KCODES 1024
#define DECAY 0.99f
#define OMD   0.01f
#define EPS   1e-5f

typedef __attribute__((ext_vector_type(8))) short short8;
typedef __attribute__((ext_vector_type(4))) float f32x4;

// ws layout (float offsets): [counts 1024][offs i32 1024][cursor i32 1024][inv 1024][en2h 1024][bucket i32 32768]
#define WS_COUNTS 0
#define WS_OFFS   1024
#define WS_CURSOR 2048
#define WS_INV    3072
#define WS_EN2H   4096
#define WS_BUCKET 5120

__device__ __forceinline__ unsigned short f2bf(float f) {
  union { float f; unsigned int u; } cv; cv.f = f;
  unsigned int u = cv.u;
  return (unsigned short)((u + 0x7fffu + ((u >> 16) & 1u)) >> 16);  // RNE
}

// ---- K1: split x into (xh, xl) bf16, MFMA A-fragment layout.
// xpack frag (mt, kb): kb 0-3 = xh, kb 4-7 = xl. 16.78 MB, aliased into out_q. ----
__global__ __launch_bounds__(256) void pack_x(const float* __restrict__ x,
                                              ushort* __restrict__ xpack) {
  const int tid = threadIdx.x;
  const int w = tid >> 6, lane = tid & 63;
  const int mt = blockIdx.x * 4 + w;          // 2048 tiles of 16 rows
  const int m = lane & 15, q = lane >> 4;
  const int row = mt * 16 + m;
  const float* xp = x + (size_t)row * DDIM + q * 8;
  #pragma unroll
  for (int kb = 0; kb < 4; ++kb) {
    float4 v0 = *(const float4*)(xp + kb * 32);
    float4 v1 = *(const float4*)(xp + kb * 32 + 4);
    float v[8] = {v0.x, v0.y, v0.z, v0.w, v1.x, v1.y, v1.z, v1.w};
    unsigned int h[8], l[8];
    #pragma unroll
    for (int j = 0; j < 8; ++j) {
      h[j] = f2bf(v[j]);
      float fh = __uint_as_float(h[j] << 16);
      l[j] = f2bf(v[j] - fh);
    }
    uint4 ph, pl;
    ph.x = h[0] | (h[1] << 16); ph.y = h[2] | (h[3] << 16);
    ph.z = h[4] | (h[5] << 16); ph.w = h[6] | (h[7] << 16);
    pl.x = l[0] | (l[1] << 16); pl.y = l[2] | (l[3] << 16);
    pl.z = l[4] | (l[5] << 16); pl.w = l[6] | (l[7] << 16);
    *(uint4*)(xpack + (((size_t)mt * 8 + kb) * 64 + lane) * 8)     = ph;
    *(uint4*)(xpack + (((size_t)mt * 8 + kb + 4) * 64 + lane) * 8) = pl;
  }
}

// ---- K2: split embed into (eh, el), MFMA B-fragment layout (no dup) + fp32 norms.
// epack frag (nt, j): j 0-3 = eh, j 4-7 = el. 512 KB, aliased into out_nea. ----
__global__ __launch_bounds__(256) void pack_e(const float* __restrict__ embed,
                                              ushort* __restrict__ epack,
                                              float* __restrict__ en2h) {
  const int tid = threadIdx.x;
  const int w = tid >> 6, lane = tid & 63;
  const int nt = blockIdx.x * 4 + w;          // 64 tiles of 16 codes
  const int m = lane & 15, q = lane >> 4;
  const int row = nt * 16 + m;
  const float* ep = embed + (size_t)row * DDIM + q * 8;
  float ss = 0.f;
  #pragma unroll
  for (int kb = 0; kb < 4; ++kb) {
    float4 v0 = *(const float4*)(ep + kb * 32);
    float4 v1 = *(const float4*)(ep + kb * 32 + 4);
    float v[8] = {v0.x, v0.y, v0.z, v0.w, v1.x, v1.y, v1.z, v1.w};
    unsigned int h[8], l[8];
    #pragma unroll
    for (int j = 0; j < 8; ++j) {
      ss += v[j] * v[j];
      h[j] = f2bf(v[j]);
      float fh = __uint_as_float(h[j] << 16);
      l[j] = f2bf(v[j] - fh);
    }
    uint4 ph, pl;
    ph.x = h[0] | (h[1] << 16); ph.y = h[2] | (h[3] << 16);
    ph.z = h[4] | (h[5] << 16); ph.w = h[6] | (h[7] << 16);
    pl.x = l[0] | (l[1] << 16); pl.y = l[2] | (l[3] << 16);
    pl.z = l[4] | (l[5] << 16); pl.w = l[6] | (l[7] << 16);
    *(uint4*)(epack + (((size_t)nt * 8 + kb) * 64 + lane) * 8)     = ph;  // eh
    *(uint4*)(epack + (((size_t)nt * 8 + kb + 4) * 64 + lane) * 8) = pl;  // el
  }
  ss += __shfl_xor(ss, 16, 64);
  ss += __shfl_xor(ss, 32, 64);
  if (q == 0) en2h[row] = 0.5f * ss;
}

// ---- K3: MFMA scoring. Block = 64 rows (4 M-tiles); wave w = code quarter w.
// B read direct from global (L2-resident 512 KB), no main-loop barriers.
// K=384 compensated: xh.eh + xl.eh + xh.el, eh regs reused. ----
__global__ __launch_bounds__(256, 2) void vq_mfma(
    const short8* __restrict__ xp8, const short8* __restrict__ ep8,
    const float* __restrict__ en2h,
    float* __restrict__ counts, float* __restrict__ out_ind) {
  __shared__ unsigned long long keys[4][64];
  const int tid = threadIdx.x;
  const int w = tid >> 6, lane = tid & 63;
  const int c = lane & 15, q = lane >> 4;
  const int mt0 = blockIdx.x * 4;             // 4 M-tiles = 64 rows
  const int nt0 = w * 16;                     // wave's quarter (16 N-tiles)

  // A fragments: 4 M-tiles x (xh 0-3, xl 4-7) = 128 VGPRs
  short8 a[4][8];
  #pragma unroll
  for (int t = 0; t < 4; ++t)
    #pragma unroll
    for (int kb = 0; kb < 8; ++kb)
      a[t][kb] = xp8[((size_t)(mt0 + t) * 8 + kb) * 64 + lane];

  float bestv[16]; int besti[16];
  #pragma unroll
  for (int i = 0; i < 16; ++i) { bestv[i] = -3.4e38f; besti[i] = 0; }

  for (int ch = 0; ch < 16; ++ch) {
    const int nt = nt0 + ch;
    short8 st[8];                             // eh 0-3, el 4-7
    #pragma unroll
    for (int j = 0; j < 8; ++j)
      st[j] = ep8[((size_t)nt * 8 + j) * 64 + lane];
    const float nh = en2h[nt * 16 + c];
    f32x4 acc[4];
    #pragma unroll
    for (int t = 0; t < 4; ++t) acc[t] = (f32x4){0.f, 0.f, 0.f, 0.f};
    #pragma unroll
    for (int t = 0; t < 4; ++t) {
      #pragma unroll
      for (int kb = 0; kb < 4; ++kb)          // xh . eh
        acc[t] = __builtin_amdgcn_mfma_f32_16x16x32_bf16(a[t][kb], st[kb], acc[t], 0, 0, 0);
      #pragma unroll
      for (int kb = 0; kb < 4; ++kb)          // xl . eh (eh reg reuse)
        acc[t] = __builtin_amdgcn_mfma_f32_16x16x32_bf16(a[t][4 + kb], st[kb], acc[t], 0, 0, 0);
      #pragma unroll
      for (int kb = 0; kb < 4; ++kb)          // xh . el
        acc[t] = __builtin_amdgcn_mfma_f32_16x16x32_bf16(a[t][kb], st[4 + kb], acc[t], 0, 0, 0);
    }
    const int code = nt * 16 + c;
    #pragma unroll
    for (int t = 0; t < 4; ++t)
      #pragma unroll
      for (int r = 0; r < 4; ++r) {           // C/D: col=lane&15, row=q*4+r
        float s = acc[t][r] - nh;
        int i = t * 4 + r;
        if (s > bestv[i]) { bestv[i] = s; besti[i] = code; }  // first-max in-stream
      }
  }

  // in-wave fold across the 16 code-columns (same q)
  #pragma unroll
  for (int off = 1; off < 16; off <<= 1) {
    #pragma unroll
    for (int i = 0; i < 16; ++i) {
      float ov = __shfl_xor(bestv[i], off, 64);
      int   oi = __shfl_xor(besti[i], off, 64);
      if (ov > bestv[i] || (ov == bestv[i] && oi < besti[i])) {
        bestv[i] = ov; besti[i] = oi;
      }
    }
  }
  if (c == 0) {
    #pragma unroll
    for (int t = 0; t < 4; ++t)
      #pragma unroll
      for (int r = 0; r < 4; ++r) {
        unsigned u = __float_as_uint(bestv[t * 4 + r]);
        unsigned su = (u & 0x80000000u) ? ~u : (u | 0x80000000u);
        keys[w][t * 16 + q * 4 + r] =
            ((unsigned long long)su << 32) |
            (unsigned long long)(0xFFFFFFFFu - (unsigned)besti[t * 4 + r]);
      }
  }
  __syncthreads();
  if (tid < 64) {                             // merge 4 quarters; ~idx => lowest code ties
    unsigned long long k0 = keys[0][tid], k1 = keys[1][tid];
    unsigned long long k2 = keys[2][tid], k3 = keys[3][tid];
    unsigned long long k = k0 > k1 ? k0 : k1;
    if (k2 > k) k = k2;
    if (k3 > k) k = k3;
    int code = (int)(0xFFFFFFFFu - (unsigned)(k & 0xFFFFFFFFull));
    out_ind[blockIdx.x * 64 + tid] = (float)code;
    unsafeAtomicAdd(counts + code, 1.0f);
  }
}

// ---- K4: fused scan(counts) + EMA cluster-size + inv ----
__global__ void scan_fin(const float* __restrict__ counts, const float* __restrict__ cs,
                         int* __restrict__ offs, int* __restrict__ cursor,
                         float* __restrict__ out_ncs, float* __restrict__ inv) {
  __shared__ float wtot[16];
  __shared__ float ctot[16];
  int tid = threadIdx.x;
  int lane = tid & 63, w = tid >> 6;
  float cnum = counts[tid];
  float cv = cs[tid];
  float s = cnum;
  #pragma unroll
  for (int off = 1; off < 64; off <<= 1) {
    float v = __shfl_up(s, off, 64);
    if (lane >= off) s += v;
  }
  float r2 = cv;
  #pragma unroll
  for (int off = 32; off > 0; off >>= 1) r2 += __shfl_down(r2, off, 64);
  if (lane == 63) wtot[w] = s;
  if (lane == 0)  ctot[w] = r2;
  __syncthreads();
  if (tid < 16) {
    float v = wtot[tid];
    #pragma unroll
    for (int off = 1; off < 16; off <<= 1) {
      float p = __shfl_up(v, off, 64);
      if (tid >= off) v += p;
    }
    wtot[tid] = v;
    float t2 = ctot[tid];
    #pragma unroll
    for (int off = 8; off > 0; off >>= 1) t2 += __shfl_down(t2, off, 64);
    if (tid == 0) ctot[0] = t2;
  }
  __syncthreads();
  float prefix = (w > 0) ? wtot[w - 1] : 0.f;
  int excl = (int)(s + prefix) - (int)cnum;
  offs[tid] = excl;
  cursor[tid] = excl;
  float ncs = cv * DECAY + OMD * cnum;
  out_ncs[tid] = ncs;
  float total = ctot[0] * DECAY + OMD * (float)NROWS;
  inv[tid] = (total + (float)KCODES * EPS) / ((ncs + EPS) * total);
}

// ---- K5: scatter row ids into per-code buckets ----
__global__ void scatter_rows(const float* __restrict__ out_ind,
                             int* __restrict__ cursor, int* __restrict__ bucket) {
  int row = blockIdx.x * 256 + threadIdx.x;
  int code = (int)out_ind[row];
  int pos = atomicAdd(cursor + code, 1);
  bucket[pos] = row;
}

// ---- K6: quantize gather-write, fully coalesced stores ----
__global__ __launch_bounds__(256) void q_write(
    const float* __restrict__ out_ind, const float* __restrict__ embed,
    float* __restrict__ out_q) {
  int gid = blockIdx.x * 256 + threadIdx.x;   // 1,048,576 float4 groups
  int row = gid >> 5, c4 = gid & 31;
  int code = (int)out_ind[row];
  *(float4*)(out_q + (size_t)gid * 4) =
      *(const float4*)(embed + (size_t)code * DDIM + c4 * 4);
}

// ---- K7: per-code segmented reduction + fused EMA epilogue (no out_q) ----
__global__ __launch_bounds__(256) void esum_fin(
    const int* __restrict__ bucket, const int* __restrict__ offs,
    const float* __restrict__ counts, const float* __restrict__ x,
    const float* __restrict__ ea, const float* __restrict__ inv,
    float* __restrict__ out_nea, float* __restrict__ out_ne) {
  __shared__ float4 part[512];
  const int code = blockIdx.x;
  const int t = threadIdx.x;
  const int c8 = t & 15;
  const int h = t >> 4;
  const int start = offs[code];
  const int cnt = (int)counts[code];
  float4 a0 = {0.f, 0.f, 0.f, 0.f}, a1 = {0.f, 0.f, 0.f, 0.f};
  int i = h;
  for (; i + 16 < cnt; i += 32) {
    int rowA = bucket[start + i];
    int rowB = bucket[start + i + 16];
    const float* pa = x + (size_t)rowA * DDIM + c8 * 8;
    const float* pb = x + (size_t)rowB * DDIM + c8 * 8;
    float4 xa0 = *(const float4*)(pa), xa1 = *(const float4*)(pa + 4);
    float4 xb0 = *(const float4*)(pb), xb1 = *(const float4*)(pb + 4);
    a0.x += xa0.x + xb0.x; a0.y += xa0.y + xb0.y; a0.z += xa0.z + xb0.z; a0.w += xa0.w + xb0.w;
    a1.x += xa1.x + xb1.x; a1.y += xa1.y + xb1.y; a1.z += xa1.z + xb1.z; a1.w += xa1.w + xb1.w;
  }
  for (; i < cnt; i += 16) {
    int row = bucket[start + i];
    const float* pa = x + (size_t)row * DDIM + c8 * 8;
    float4 xa0 = *(const float4*)(pa), xa1 = *(const float4*)(pa + 4);
    a0.x += xa0.x; a0.y += xa0.y; a0.z += xa0.z; a0.w += xa0.w;
    a1.x += xa1.x; a1.y += xa1.y; a1.z += xa1.z; a1.w += xa1.w;
  }
  part[h * 32 + c8 * 2]     = a0;
  part[h * 32 + c8 * 2 + 1] = a1;
  __syncthreads();
  if (t < 32) {
    float4 s = part[t];
    #pragma unroll
    for (int hh = 1; hh < 16; ++hh) {
      float4 p = part[hh * 32 + t];
      s.x += p.x; s.y += p.y; s.z += p.z; s.w += p.w;
    }
    float iv = inv[code];
    int base = code * DDIM + t * 4;
    float4 a = *(const float4*)(ea + base);
    float4 nea;
    nea.x = a.x * DECAY + OMD * s.x; nea.y = a.y * DECAY + OMD * s.y;
    nea.z = a.z * DECAY + OMD * s.z; nea.w = a.w * DECAY + OMD * s.w;
    *(float4*)(out_nea + base) = nea;
    float4 ne;
    ne.x = nea.x * iv; ne.y = nea.y * iv; ne.z = nea.z * iv; ne.w = nea.w * iv;
    *(float4*)(out_ne + base) = ne;
  }
}

extern "C" void kernel_launch(void* const* d_in, const int* in_sizes, int n_in,
                              void* d_out, int out_size, void* d_ws, size_t ws_size,
                              hipStream_t stream) {
  const float* x     = (const float*)d_in[0];
  const float* embed = (const float*)d_in[1];
  const float* cs    = (const float*)d_in[2];
  const float* ea    = (const float*)d_in[3];

  float* out     = (float*)d_out;
  float* out_q   = out;                       // 4194304
  float* out_ind = out_q + 4194304;           // 32768
  float* out_ncs = out_ind + 32768;           // 1024
  float* out_nea = out_ncs + 1024;            // 131072
  float* out_ne  = out_nea + 131072;          // 131072

  float* ws     = (float*)d_ws;
  float* counts = ws + WS_COUNTS;
  int*   offs   = (int*)(ws + WS_OFFS);
  int*   cursor = (int*)(ws + WS_CURSOR);
  float* inv    = ws + WS_INV;
  float* en2h   = ws + WS_EN2H;
  int*   bucket = (int*)(ws + WS_BUCKET);

  // scratch aliased into d_out (regions fully rewritten later):
  ushort* xpack = (ushort*)out_q;             // 16.78 MB == out_q (q_write after vq)
  ushort* epack = (ushort*)out_nea;           // 512 KB == out_nea (esum_fin after vq)

  hipMemsetAsync(counts, 0, KCODES * sizeof(float), stream);
  pack_x<<<512, 256, 0, stream>>>(x, xpack);
  pack_e<<<16, 256, 0, stream>>>(embed, epack, en2h);
  vq_mfma<<<NROWS / 64, 256, 0, stream>>>((const short8*)xpack, (const short8*)epack,
                                          en2h, counts, out_ind);
  scan_fin<<<1, 1024, 0, stream>>>(counts, cs, offs, cursor, out_ncs, inv);
  scatter_rows<<<NROWS / 256, 256, 0, stream>>>(out_ind, cursor, bucket);
  q_write<<<(NROWS * 32) / 256, 256, 0, stream>>>(out_ind, embed, out_q);
  esum_fin<<<KCODES, 256, 0, stream>>>(bucket, offs, counts, x, ea, inv,
                                       out_nea, out_ne);
}